// Round 2
// baseline (884.169 us; speedup 1.0000x reference)
//
#include <hip/hip_runtime.h>

constexpr int NN = 100000;     // nodes
constexpr int NE = 3200000;    // edges
constexpr int D0 = 256;        // in dim
constexpr int D1 = 128;        // hidden 1
constexpr int D2 = 64;         // hidden 2

constexpr int NB_NODE = (NN + 255) / 256;   // 391
constexpr int NB_EDGE = (NE + 255) / 256;   // 12500

// ---------------- degree / dinv ----------------
__global__ __launch_bounds__(256) void count_deg_k(const int* __restrict__ rows,
                                                   unsigned* __restrict__ deg) {
  int e = blockIdx.x * 256 + threadIdx.x;
  if (e < NE) atomicAdd(&deg[rows[e]], 1u);
}

__global__ __launch_bounds__(256) void dinv_k(const unsigned* __restrict__ deg,
                                              float* __restrict__ dinv) {
  int i = blockIdx.x * 256 + threadIdx.x;
  if (i < NN) dinv[i] = rsqrtf((float)(deg[i] + 1u));  // +1 for self loop
}

// ---------------- exclusive scan (3-kernel) ----------------
__global__ __launch_bounds__(256) void scan1_k(const unsigned* __restrict__ deg,
                                               unsigned* __restrict__ row_start,
                                               unsigned* __restrict__ blockSums) {
  __shared__ unsigned s[256];
  int i = blockIdx.x * 256 + threadIdx.x;
  unsigned v = (i < NN) ? deg[i] : 0u;
  s[threadIdx.x] = v;
  __syncthreads();
  for (int off = 1; off < 256; off <<= 1) {
    unsigned t = (threadIdx.x >= off) ? s[threadIdx.x - off] : 0u;
    __syncthreads();
    s[threadIdx.x] += t;
    __syncthreads();
  }
  if (i < NN) row_start[i] = s[threadIdx.x] - v;  // exclusive
  if (threadIdx.x == 255) blockSums[blockIdx.x] = s[255];
}

__global__ __launch_bounds__(512) void scan2_k(const unsigned* __restrict__ blockSums,
                                               unsigned* __restrict__ blockOffs,
                                               unsigned* __restrict__ row_start) {
  __shared__ unsigned s[512];
  int i = threadIdx.x;
  unsigned v = (i < NB_NODE) ? blockSums[i] : 0u;
  s[i] = v;
  __syncthreads();
  for (int off = 1; off < 512; off <<= 1) {
    unsigned t = (i >= off) ? s[i - off] : 0u;
    __syncthreads();
    s[i] += t;
    __syncthreads();
  }
  if (i < NB_NODE) blockOffs[i] = s[i] - v;  // exclusive
  if (i == 511) row_start[NN] = s[511];      // total == NE
}

__global__ __launch_bounds__(256) void scan3_k(unsigned* __restrict__ row_start,
                                               const unsigned* __restrict__ blockOffs) {
  int i = blockIdx.x * 256 + threadIdx.x;
  if (i < NN) row_start[i] += blockOffs[blockIdx.x];
}

// ---------------- CSR fill ----------------
__global__ __launch_bounds__(256) void fill_csr_k(const int* __restrict__ rows,
                                                  const int* __restrict__ cols,
                                                  const unsigned* __restrict__ row_start,
                                                  unsigned* __restrict__ cursor,
                                                  int* __restrict__ col_sorted) {
  int e = blockIdx.x * 256 + threadIdx.x;
  if (e < NE) {
    int r = rows[e];
    unsigned pos = row_start[r] + atomicAdd(&cursor[r], 1u);
    col_sorted[pos] = cols[e];
  }
}

// ---------------- tiled fp32 GEMM with dinv epilogue scale ----------------
// out[r][c] = dinv[r] * sum_k A[r][k] * W[k][c]      (BN == full output width)
template <int BM, int BN, int BK, int TM, int TN, int K>
__global__ __launch_bounds__(256) void gemm_scale_k(const float* __restrict__ A,
                                                    const float* __restrict__ W,
                                                    const float* __restrict__ dinv,
                                                    float* __restrict__ out, int M) {
  constexpr int TX = BN / TN;
  constexpr int TY = BM / TM;
  static_assert(TX * TY == 256, "thread shape");
  __shared__ float As[BK][BM];   // A tile, transposed
  __shared__ float Ws[BK][BN];   // W tile
  const int tid = threadIdx.x;
  const int tx = tid % TX, ty = tid / TX;
  const int rowBase = blockIdx.x * BM;

  float acc[TM][TN];
#pragma unroll
  for (int i = 0; i < TM; i++)
#pragma unroll
    for (int j = 0; j < TN; j++) acc[i][j] = 0.f;

  constexpr int AF4 = BM * BK / 4 / 256;
  constexpr int WF4 = BK * BN / 4 / 256;

  for (int k0 = 0; k0 < K; k0 += BK) {
#pragma unroll
    for (int q = 0; q < AF4; q++) {
      int f = tid + q * 256;
      int r = f / (BK / 4);
      int kk = (f % (BK / 4)) * 4;
      float4 v = make_float4(0.f, 0.f, 0.f, 0.f);
      int gr = rowBase + r;
      if (gr < M) v = *(const float4*)&A[(size_t)gr * K + k0 + kk];
      As[kk + 0][r] = v.x;
      As[kk + 1][r] = v.y;
      As[kk + 2][r] = v.z;
      As[kk + 3][r] = v.w;
    }
#pragma unroll
    for (int q = 0; q < WF4; q++) {
      int f = tid + q * 256;
      int kk = f / (BN / 4);
      int c = (f % (BN / 4)) * 4;
      *(float4*)&Ws[kk][c] = *(const float4*)&W[(size_t)(k0 + kk) * BN + c];
    }
    __syncthreads();
#pragma unroll
    for (int kk = 0; kk < BK; kk++) {
      float a[TM], wv[TN];
#pragma unroll
      for (int i = 0; i < TM; i += 4) {
        float4 t = *(const float4*)&As[kk][ty * TM + i];
        a[i] = t.x; a[i + 1] = t.y; a[i + 2] = t.z; a[i + 3] = t.w;
      }
#pragma unroll
      for (int j = 0; j < TN; j += 4) {
        float4 t = *(const float4*)&Ws[kk][tx * TN + j];
        wv[j] = t.x; wv[j + 1] = t.y; wv[j + 2] = t.z; wv[j + 3] = t.w;
      }
#pragma unroll
      for (int i = 0; i < TM; i++)
#pragma unroll
        for (int j = 0; j < TN; j++) acc[i][j] += a[i] * wv[j];
    }
    __syncthreads();
  }

#pragma unroll
  for (int i = 0; i < TM; i++) {
    int gr = rowBase + ty * TM + i;
    if (gr < M) {
      float d = dinv[gr];
#pragma unroll
      for (int j = 0; j < TN; j += 4) {
        float4 o;
        o.x = acc[i][j + 0] * d;
        o.y = acc[i][j + 1] * d;
        o.z = acc[i][j + 2] * d;
        o.w = acc[i][j + 3] * d;
        *(float4*)&out[(size_t)gr * BN + tx * TN + j] = o;
      }
    }
  }
}

// ---------------- propagation: wave-per-node gather-accumulate ----------------
// layer 1: 128 features -> float2 per lane
__global__ __launch_bounds__(256) void prop1_k(const float* __restrict__ hp,      // h*dinv [NN][128]
                                               const unsigned* __restrict__ row_start,
                                               const int* __restrict__ cols,
                                               const float* __restrict__ dinv,
                                               const float* __restrict__ bias,
                                               float* __restrict__ out) {        // h1 [NN][128]
  int wid = (blockIdx.x * 256 + threadIdx.x) >> 6;
  int lane = threadIdx.x & 63;
  if (wid >= NN) return;
  const int r = wid;
  float2 a0 = *(const float2*)&hp[(size_t)r * D1 + lane * 2];  // self loop
  float2 a1 = make_float2(0.f, 0.f), a2 = make_float2(0.f, 0.f), a3 = make_float2(0.f, 0.f);
  unsigned s = row_start[r], e = row_start[r + 1];
  for (unsigned base = s; base < e; base += 64) {
    int cnt = (int)min(64u, e - base);
    int c = (lane < cnt) ? cols[base + lane] : 0;
    int j = 0;
    for (; j + 4 <= cnt; j += 4) {
      int c0 = __shfl(c, j), c1 = __shfl(c, j + 1), c2 = __shfl(c, j + 2), c3 = __shfl(c, j + 3);
      float2 v0 = *(const float2*)&hp[(size_t)c0 * D1 + lane * 2];
      float2 v1 = *(const float2*)&hp[(size_t)c1 * D1 + lane * 2];
      float2 v2 = *(const float2*)&hp[(size_t)c2 * D1 + lane * 2];
      float2 v3 = *(const float2*)&hp[(size_t)c3 * D1 + lane * 2];
      a0.x += v0.x; a0.y += v0.y;
      a1.x += v1.x; a1.y += v1.y;
      a2.x += v2.x; a2.y += v2.y;
      a3.x += v3.x; a3.y += v3.y;
    }
    for (; j < cnt; j++) {
      int cj = __shfl(c, j);
      float2 v = *(const float2*)&hp[(size_t)cj * D1 + lane * 2];
      a0.x += v.x; a0.y += v.y;
    }
  }
  float dr = dinv[r];
  float2 b = *(const float2*)&bias[lane * 2];
  float2 o;
  o.x = fmaxf((a0.x + a1.x + a2.x + a3.x) * dr + b.x, 0.f);
  o.y = fmaxf((a0.y + a1.y + a2.y + a3.y) * dr + b.y, 0.f);
  *(float2*)&out[(size_t)r * D1 + lane * 2] = o;
}

// layer 2: 64 features -> 1 float per lane
__global__ __launch_bounds__(256) void prop2_k(const float* __restrict__ hp,      // h2*dinv [NN][64]
                                               const unsigned* __restrict__ row_start,
                                               const int* __restrict__ cols,
                                               const float* __restrict__ dinv,
                                               const float* __restrict__ bias,
                                               float* __restrict__ out) {        // z [NN][64]
  int wid = (blockIdx.x * 256 + threadIdx.x) >> 6;
  int lane = threadIdx.x & 63;
  if (wid >= NN) return;
  const int r = wid;
  float a0 = hp[(size_t)r * D2 + lane];  // self loop
  float a1 = 0.f, a2 = 0.f, a3 = 0.f;
  unsigned s = row_start[r], e = row_start[r + 1];
  for (unsigned base = s; base < e; base += 64) {
    int cnt = (int)min(64u, e - base);
    int c = (lane < cnt) ? cols[base + lane] : 0;
    int j = 0;
    for (; j + 4 <= cnt; j += 4) {
      int c0 = __shfl(c, j), c1 = __shfl(c, j + 1), c2 = __shfl(c, j + 2), c3 = __shfl(c, j + 3);
      a0 += hp[(size_t)c0 * D2 + lane];
      a1 += hp[(size_t)c1 * D2 + lane];
      a2 += hp[(size_t)c2 * D2 + lane];
      a3 += hp[(size_t)c3 * D2 + lane];
    }
    for (; j < cnt; j++) {
      int cj = __shfl(c, j);
      a0 += hp[(size_t)cj * D2 + lane];
    }
  }
  float dr = dinv[r];
  out[(size_t)r * D2 + lane] = fmaxf((a0 + a1 + a2 + a3) * dr + bias[lane], 0.f);
}

// ---------------- launcher ----------------
extern "C" void kernel_launch(void* const* d_in, const int* in_sizes, int n_in,
                              void* d_out, int out_size, void* d_ws, size_t ws_size,
                              hipStream_t stream) {
  const float* x = (const float*)d_in[0];
  const int* ei = (const int*)d_in[1];       // int64 in reference -> int32 here
  const float* W1 = (const float*)d_in[2];
  const float* b1 = (const float*)d_in[3];
  const float* W2 = (const float*)d_in[4];
  const float* b2 = (const float*)d_in[5];
  float* z = (float*)d_out;

  const int* rows = ei;         // edge_index[0] (targets)
  const int* cols = ei + NE;    // edge_index[1] (sources)

  auto align_up = [](size_t v) { return (v + 511) & ~(size_t)511; };
  char* w = (char*)d_ws;
  unsigned* deg = (unsigned*)w;        w += align_up((size_t)NN * 4);
  float* dinv = (float*)w;             w += align_up((size_t)NN * 4);
  unsigned* row_start = (unsigned*)w;  w += align_up((size_t)(NN + 1) * 4);
  unsigned* cursor = (unsigned*)w;     w += align_up((size_t)NN * 4);
  unsigned* blockSums = (unsigned*)w;  w += align_up((size_t)NB_NODE * 4);
  unsigned* blockOffs = (unsigned*)w;  w += align_up((size_t)NB_NODE * 4);
  int* col_sorted = (int*)w;           w += align_up((size_t)NE * 4);
  float* bufA = (float*)w;             w += align_up((size_t)NN * D1 * 4);  // h' then h2'
  float* bufB = (float*)w;             w += align_up((size_t)NN * D1 * 4);  // h1

  hipMemsetAsync(deg, 0, (size_t)NN * 4, stream);
  hipMemsetAsync(cursor, 0, (size_t)NN * 4, stream);

  count_deg_k<<<NB_EDGE, 256, 0, stream>>>(rows, deg);
  dinv_k<<<NB_NODE, 256, 0, stream>>>(deg, dinv);
  scan1_k<<<NB_NODE, 256, 0, stream>>>(deg, row_start, blockSums);
  scan2_k<<<1, 512, 0, stream>>>(blockSums, blockOffs, row_start);
  scan3_k<<<NB_NODE, 256, 0, stream>>>(row_start, blockOffs);
  fill_csr_k<<<NB_EDGE, 256, 0, stream>>>(rows, cols, row_start, cursor, col_sorted);

  // layer 1: h' = (x @ W1) * dinv ; h1 = relu(dinv*(sum_neighbors h' + h'_self) + b1)
  gemm_scale_k<64, 128, 32, 8, 4, 256><<<(NN + 63) / 64, 256, 0, stream>>>(x, W1, dinv, bufA, NN);
  prop1_k<<<(NN + 3) / 4, 256, 0, stream>>>(bufA, row_start, col_sorted, dinv, b1, bufB);

  // layer 2: h2' = (h1 @ W2) * dinv ; z = relu(dinv*(sum + self) + b2)
  gemm_scale_k<64, 64, 32, 4, 4, 128><<<(NN + 63) / 64, 256, 0, stream>>>(bufB, W2, dinv, bufA, NN);
  prop2_k<<<(NN + 3) / 4, 256, 0, stream>>>(bufA, row_start, col_sorted, dinv, b2, z);
}

// Round 3
// 718.653 us; speedup vs baseline: 1.2303x; 1.2303x over previous
//
#include <hip/hip_runtime.h>

constexpr int NN = 100000;     // nodes
constexpr int NE = 3200000;    // edges
constexpr int D0 = 256;        // in dim
constexpr int D1 = 128;        // hidden 1
constexpr int D2 = 64;         // hidden 2

constexpr int NB_NODE = (NN + 255) / 256;   // 391
constexpr int NB_EDGE = (NE + 255) / 256;   // 12500

typedef unsigned short ushort8v __attribute__((ext_vector_type(8)));

static __device__ __forceinline__ float bf2f(unsigned short u) {
  return __uint_as_float(((unsigned)u) << 16);
}
static __device__ __forceinline__ unsigned short f2bf(float x) {
  unsigned u = __float_as_uint(x);
  unsigned r = (u + 0x7FFFu + ((u >> 16) & 1u)) >> 16;   // RNE
  return (unsigned short)r;
}

// ---------------- degree / dinv ----------------
__global__ __launch_bounds__(256) void count_deg_k(const int* __restrict__ rows,
                                                   unsigned* __restrict__ deg) {
  int e = blockIdx.x * 256 + threadIdx.x;
  if (e < NE) atomicAdd(&deg[rows[e]], 1u);
}

__global__ __launch_bounds__(256) void dinv_k(const unsigned* __restrict__ deg,
                                              float* __restrict__ dinv) {
  int i = blockIdx.x * 256 + threadIdx.x;
  if (i < NN) dinv[i] = rsqrtf((float)(deg[i] + 1u));  // +1 for self loop
}

// ---------------- exclusive scan (3-kernel) ----------------
__global__ __launch_bounds__(256) void scan1_k(const unsigned* __restrict__ deg,
                                               unsigned* __restrict__ row_start,
                                               unsigned* __restrict__ blockSums) {
  __shared__ unsigned s[256];
  int i = blockIdx.x * 256 + threadIdx.x;
  unsigned v = (i < NN) ? deg[i] : 0u;
  s[threadIdx.x] = v;
  __syncthreads();
  for (int off = 1; off < 256; off <<= 1) {
    unsigned t = (threadIdx.x >= off) ? s[threadIdx.x - off] : 0u;
    __syncthreads();
    s[threadIdx.x] += t;
    __syncthreads();
  }
  if (i < NN) row_start[i] = s[threadIdx.x] - v;  // exclusive
  if (threadIdx.x == 255) blockSums[blockIdx.x] = s[255];
}

__global__ __launch_bounds__(512) void scan2_k(const unsigned* __restrict__ blockSums,
                                               unsigned* __restrict__ blockOffs,
                                               unsigned* __restrict__ row_start) {
  __shared__ unsigned s[512];
  int i = threadIdx.x;
  unsigned v = (i < NB_NODE) ? blockSums[i] : 0u;
  s[i] = v;
  __syncthreads();
  for (int off = 1; off < 512; off <<= 1) {
    unsigned t = (i >= off) ? s[i - off] : 0u;
    __syncthreads();
    s[i] += t;
    __syncthreads();
  }
  if (i < NB_NODE) blockOffs[i] = s[i] - v;  // exclusive
  if (i == 511) row_start[NN] = s[511];      // total == NE
}

__global__ __launch_bounds__(256) void scan3_k(unsigned* __restrict__ row_start,
                                               const unsigned* __restrict__ blockOffs) {
  int i = blockIdx.x * 256 + threadIdx.x;
  if (i < NN) row_start[i] += blockOffs[blockIdx.x];
}

// ---------------- CSR fill ----------------
__global__ __launch_bounds__(256) void fill_csr_k(const int* __restrict__ rows,
                                                  const int* __restrict__ cols,
                                                  const unsigned* __restrict__ row_start,
                                                  unsigned* __restrict__ cursor,
                                                  int* __restrict__ col_sorted) {
  int e = blockIdx.x * 256 + threadIdx.x;
  if (e < NE) {
    int r = rows[e];
    unsigned pos = row_start[r] + atomicAdd(&cursor[r], 1u);
    col_sorted[pos] = cols[e];
  }
}

// ---------------- tiled fp32 GEMM, dinv epilogue scale, optional bf16 out ----
// out[r][c] = dinv[r] * sum_k A[r][k] * W[k][c]      (BN == full output width)
template <int BM, int BN, int BK, int TM, int TN, int K, bool BF16_OUT>
__global__ __launch_bounds__(256) void gemm_scale_k(const float* __restrict__ A,
                                                    const float* __restrict__ W,
                                                    const float* __restrict__ dinv,
                                                    void* __restrict__ outp, int M) {
  constexpr int TX = BN / TN;
  constexpr int TY = BM / TM;
  static_assert(TX * TY == 256, "thread shape");
  __shared__ float As[BK][BM];   // A tile, transposed
  __shared__ float Ws[BK][BN];   // W tile
  const int tid = threadIdx.x;
  const int tx = tid % TX, ty = tid / TX;
  const int rowBase = blockIdx.x * BM;

  float acc[TM][TN];
#pragma unroll
  for (int i = 0; i < TM; i++)
#pragma unroll
    for (int j = 0; j < TN; j++) acc[i][j] = 0.f;

  constexpr int AF4 = BM * BK / 4 / 256;
  constexpr int WF4 = BK * BN / 4 / 256;

  for (int k0 = 0; k0 < K; k0 += BK) {
#pragma unroll
    for (int q = 0; q < AF4; q++) {
      int f = tid + q * 256;
      int r = f / (BK / 4);
      int kk = (f % (BK / 4)) * 4;
      float4 v = make_float4(0.f, 0.f, 0.f, 0.f);
      int gr = rowBase + r;
      if (gr < M) v = *(const float4*)&A[(size_t)gr * K + k0 + kk];
      As[kk + 0][r] = v.x;
      As[kk + 1][r] = v.y;
      As[kk + 2][r] = v.z;
      As[kk + 3][r] = v.w;
    }
#pragma unroll
    for (int q = 0; q < WF4; q++) {
      int f = tid + q * 256;
      int kk = f / (BN / 4);
      int c = (f % (BN / 4)) * 4;
      *(float4*)&Ws[kk][c] = *(const float4*)&W[(size_t)(k0 + kk) * BN + c];
    }
    __syncthreads();
#pragma unroll
    for (int kk = 0; kk < BK; kk++) {
      float a[TM], wv[TN];
#pragma unroll
      for (int i = 0; i < TM; i += 4) {
        float4 t = *(const float4*)&As[kk][ty * TM + i];
        a[i] = t.x; a[i + 1] = t.y; a[i + 2] = t.z; a[i + 3] = t.w;
      }
#pragma unroll
      for (int j = 0; j < TN; j += 4) {
        float4 t = *(const float4*)&Ws[kk][tx * TN + j];
        wv[j] = t.x; wv[j + 1] = t.y; wv[j + 2] = t.z; wv[j + 3] = t.w;
      }
#pragma unroll
      for (int i = 0; i < TM; i++)
#pragma unroll
        for (int j = 0; j < TN; j++) acc[i][j] += a[i] * wv[j];
    }
    __syncthreads();
  }

#pragma unroll
  for (int i = 0; i < TM; i++) {
    int gr = rowBase + ty * TM + i;
    if (gr < M) {
      float d = dinv[gr];
      if constexpr (BF16_OUT) {
        unsigned short* out = (unsigned short*)outp;
#pragma unroll
        for (int j = 0; j < TN; j += 4) {
          ushort4 o;
          o.x = f2bf(acc[i][j + 0] * d);
          o.y = f2bf(acc[i][j + 1] * d);
          o.z = f2bf(acc[i][j + 2] * d);
          o.w = f2bf(acc[i][j + 3] * d);
          *(ushort4*)&out[(size_t)gr * BN + tx * TN + j] = o;
        }
      } else {
        float* out = (float*)outp;
#pragma unroll
        for (int j = 0; j < TN; j += 4) {
          float4 o;
          o.x = acc[i][j + 0] * d;
          o.y = acc[i][j + 1] * d;
          o.z = acc[i][j + 2] * d;
          o.w = acc[i][j + 3] * d;
          *(float4*)&out[(size_t)gr * BN + tx * TN + j] = o;
        }
      }
    }
  }
}

// ---------------- propagation: wave-per-node, bf16 payload gather ----------
// layer 1: 128 bf16 feats/row (256B). 16 lanes x 16B cover a row ->
// 4 neighbors per wave-load. q = lane>>4 selects neighbor-within-group,
// f = lane&15 selects feature slice [f*8 .. f*8+7].
__global__ __launch_bounds__(256) void prop1_k(const unsigned short* __restrict__ hp,
                                               const unsigned* __restrict__ row_start,
                                               const int* __restrict__ cols,
                                               const float* __restrict__ dinv,
                                               const float* __restrict__ bias,
                                               float* __restrict__ out) {  // h1 f32 [NN][128]
  int wid = (blockIdx.x * 256 + threadIdx.x) >> 6;
  int lane = threadIdx.x & 63;
  if (wid >= NN) return;
  const int r = wid;
  const int q = lane >> 4, f = lane & 15;

  float a0[8], a1[8];
#pragma unroll
  for (int k = 0; k < 8; k++) { a0[k] = 0.f; a1[k] = 0.f; }
  if (q == 0) {  // self loop, counted once
    ushort8v v = *(const ushort8v*)(hp + (size_t)r * D1 + f * 8);
#pragma unroll
    for (int k = 0; k < 8; k++) a0[k] = bf2f(v[k]);
  }

  unsigned s = row_start[r], e = row_start[r + 1];
  for (unsigned base = s; base < e; base += 64) {
    int cnt = (int)min(64u, e - base);
    int c = (lane < cnt) ? cols[base + lane] : 0;
    int j = 0;
    for (; j + 8 <= cnt; j += 8) {
      int c0 = __shfl(c, j + q);
      int c1 = __shfl(c, j + 4 + q);
      ushort8v v0 = *(const ushort8v*)(hp + (size_t)c0 * D1 + f * 8);
      ushort8v v1 = *(const ushort8v*)(hp + (size_t)c1 * D1 + f * 8);
#pragma unroll
      for (int k = 0; k < 8; k++) a0[k] += bf2f(v0[k]);
#pragma unroll
      for (int k = 0; k < 8; k++) a1[k] += bf2f(v1[k]);
    }
    for (; j + 4 <= cnt; j += 4) {
      int c0 = __shfl(c, j + q);
      ushort8v v0 = *(const ushort8v*)(hp + (size_t)c0 * D1 + f * 8);
#pragma unroll
      for (int k = 0; k < 8; k++) a0[k] += bf2f(v0[k]);
    }
    if (j < cnt) {
      int c0 = __shfl(c, j + q);
      if (j + q < cnt) {
        ushort8v v0 = *(const ushort8v*)(hp + (size_t)c0 * D1 + f * 8);
#pragma unroll
        for (int k = 0; k < 8; k++) a0[k] += bf2f(v0[k]);
      }
    }
  }

#pragma unroll
  for (int k = 0; k < 8; k++) a0[k] += a1[k];
  // reduce across the 4 q-groups
#pragma unroll
  for (int k = 0; k < 8; k++) a0[k] += __shfl_xor(a0[k], 16);
#pragma unroll
  for (int k = 0; k < 8; k++) a0[k] += __shfl_xor(a0[k], 32);

  if (q == 0) {
    float dr = dinv[r];
    float4 b0 = *(const float4*)&bias[f * 8];
    float4 b1v = *(const float4*)&bias[f * 8 + 4];
    float4 o0, o1;
    o0.x = fmaxf(a0[0] * dr + b0.x, 0.f);
    o0.y = fmaxf(a0[1] * dr + b0.y, 0.f);
    o0.z = fmaxf(a0[2] * dr + b0.z, 0.f);
    o0.w = fmaxf(a0[3] * dr + b0.w, 0.f);
    o1.x = fmaxf(a0[4] * dr + b1v.x, 0.f);
    o1.y = fmaxf(a0[5] * dr + b1v.y, 0.f);
    o1.z = fmaxf(a0[6] * dr + b1v.z, 0.f);
    o1.w = fmaxf(a0[7] * dr + b1v.w, 0.f);
    *(float4*)&out[(size_t)r * D1 + f * 8] = o0;
    *(float4*)&out[(size_t)r * D1 + f * 8 + 4] = o1;
  }
}

// layer 2: 64 bf16 feats/row (128B). 8 lanes x 16B -> 8 neighbors per load.
__global__ __launch_bounds__(256) void prop2_k(const unsigned short* __restrict__ hp,
                                               const unsigned* __restrict__ row_start,
                                               const int* __restrict__ cols,
                                               const float* __restrict__ dinv,
                                               const float* __restrict__ bias,
                                               float* __restrict__ out) {  // z f32 [NN][64]
  int wid = (blockIdx.x * 256 + threadIdx.x) >> 6;
  int lane = threadIdx.x & 63;
  if (wid >= NN) return;
  const int r = wid;
  const int q = lane >> 3, f = lane & 7;

  float a0[8], a1[8];
#pragma unroll
  for (int k = 0; k < 8; k++) { a0[k] = 0.f; a1[k] = 0.f; }
  if (q == 0) {  // self loop
    ushort8v v = *(const ushort8v*)(hp + (size_t)r * D2 + f * 8);
#pragma unroll
    for (int k = 0; k < 8; k++) a0[k] = bf2f(v[k]);
  }

  unsigned s = row_start[r], e = row_start[r + 1];
  for (unsigned base = s; base < e; base += 64) {
    int cnt = (int)min(64u, e - base);
    int c = (lane < cnt) ? cols[base + lane] : 0;
    int j = 0;
    for (; j + 16 <= cnt; j += 16) {
      int c0 = __shfl(c, j + q);
      int c1 = __shfl(c, j + 8 + q);
      ushort8v v0 = *(const ushort8v*)(hp + (size_t)c0 * D2 + f * 8);
      ushort8v v1 = *(const ushort8v*)(hp + (size_t)c1 * D2 + f * 8);
#pragma unroll
      for (int k = 0; k < 8; k++) a0[k] += bf2f(v0[k]);
#pragma unroll
      for (int k = 0; k < 8; k++) a1[k] += bf2f(v1[k]);
    }
    for (; j + 8 <= cnt; j += 8) {
      int c0 = __shfl(c, j + q);
      ushort8v v0 = *(const ushort8v*)(hp + (size_t)c0 * D2 + f * 8);
#pragma unroll
      for (int k = 0; k < 8; k++) a0[k] += bf2f(v0[k]);
    }
    if (j < cnt) {
      int c0 = __shfl(c, j + q);
      if (j + q < cnt) {
        ushort8v v0 = *(const ushort8v*)(hp + (size_t)c0 * D2 + f * 8);
#pragma unroll
        for (int k = 0; k < 8; k++) a0[k] += bf2f(v0[k]);
      }
    }
  }

#pragma unroll
  for (int k = 0; k < 8; k++) a0[k] += a1[k];
  // reduce across the 8 q-groups
#pragma unroll
  for (int k = 0; k < 8; k++) a0[k] += __shfl_xor(a0[k], 8);
#pragma unroll
  for (int k = 0; k < 8; k++) a0[k] += __shfl_xor(a0[k], 16);
#pragma unroll
  for (int k = 0; k < 8; k++) a0[k] += __shfl_xor(a0[k], 32);

  if (q == 0) {
    float dr = dinv[r];
    float4 b0 = *(const float4*)&bias[f * 8];
    float4 b1v = *(const float4*)&bias[f * 8 + 4];
    float4 o0, o1;
    o0.x = fmaxf(a0[0] * dr + b0.x, 0.f);
    o0.y = fmaxf(a0[1] * dr + b0.y, 0.f);
    o0.z = fmaxf(a0[2] * dr + b0.z, 0.f);
    o0.w = fmaxf(a0[3] * dr + b0.w, 0.f);
    o1.x = fmaxf(a0[4] * dr + b1v.x, 0.f);
    o1.y = fmaxf(a0[5] * dr + b1v.y, 0.f);
    o1.z = fmaxf(a0[6] * dr + b1v.z, 0.f);
    o1.w = fmaxf(a0[7] * dr + b1v.w, 0.f);
    *(float4*)&out[(size_t)r * D2 + f * 8] = o0;
    *(float4*)&out[(size_t)r * D2 + f * 8 + 4] = o1;
  }
}

// ---------------- launcher ----------------
extern "C" void kernel_launch(void* const* d_in, const int* in_sizes, int n_in,
                              void* d_out, int out_size, void* d_ws, size_t ws_size,
                              hipStream_t stream) {
  const float* x = (const float*)d_in[0];
  const int* ei = (const int*)d_in[1];       // int64 in reference -> int32 here
  const float* W1 = (const float*)d_in[2];
  const float* b1 = (const float*)d_in[3];
  const float* W2 = (const float*)d_in[4];
  const float* b2 = (const float*)d_in[5];
  float* z = (float*)d_out;

  const int* rows = ei;         // edge_index[0] (targets)
  const int* cols = ei + NE;    // edge_index[1] (sources)

  auto align_up = [](size_t v) { return (v + 511) & ~(size_t)511; };
  char* w = (char*)d_ws;
  unsigned* deg = (unsigned*)w;        w += align_up((size_t)NN * 4);
  float* dinv = (float*)w;             w += align_up((size_t)NN * 4);
  unsigned* row_start = (unsigned*)w;  w += align_up((size_t)(NN + 1) * 4);
  unsigned* cursor = (unsigned*)w;     w += align_up((size_t)NN * 4);
  unsigned* blockSums = (unsigned*)w;  w += align_up((size_t)NB_NODE * 4);
  unsigned* blockOffs = (unsigned*)w;  w += align_up((size_t)NB_NODE * 4);
  int* col_sorted = (int*)w;           w += align_up((size_t)NE * 4);
  unsigned short* hbf = (unsigned short*)w; w += align_up((size_t)NN * D1 * 2);  // h'/h2' bf16
  float* h1 = (float*)w;               w += align_up((size_t)NN * D1 * 4);       // h1 f32

  hipMemsetAsync(deg, 0, (size_t)NN * 4, stream);
  hipMemsetAsync(cursor, 0, (size_t)NN * 4, stream);

  count_deg_k<<<NB_EDGE, 256, 0, stream>>>(rows, deg);
  dinv_k<<<NB_NODE, 256, 0, stream>>>(deg, dinv);
  scan1_k<<<NB_NODE, 256, 0, stream>>>(deg, row_start, blockSums);
  scan2_k<<<1, 512, 0, stream>>>(blockSums, blockOffs, row_start);
  scan3_k<<<NB_NODE, 256, 0, stream>>>(row_start, blockOffs);
  fill_csr_k<<<NB_EDGE, 256, 0, stream>>>(rows, cols, row_start, cursor, col_sorted);

  // layer 1: h' = bf16((x @ W1) * dinv) ; h1 = relu(dinv*(sum_nb h' + h'_self) + b1)
  gemm_scale_k<64, 128, 32, 8, 4, 256, true>
      <<<(NN + 63) / 64, 256, 0, stream>>>(x, W1, dinv, hbf, NN);
  prop1_k<<<(NN + 3) / 4, 256, 0, stream>>>(hbf, row_start, col_sorted, dinv, b1, h1);

  // layer 2: h2' = bf16((h1 @ W2) * dinv) ; z = relu(dinv*(sum + self) + b2)
  gemm_scale_k<64, 64, 32, 4, 4, 128, true>
      <<<(NN + 63) / 64, 256, 0, stream>>>(h1, W2, dinv, hbf, NN);
  prop2_k<<<(NN + 3) / 4, 256, 0, stream>>>(hbf, row_start, col_sorted, dinv, b2, z);
}

// Round 4
// 537.468 us; speedup vs baseline: 1.6451x; 1.3371x over previous
//
#include <hip/hip_runtime.h>

constexpr int NN = 100000;     // nodes
constexpr int NE = 3200000;    // edges
constexpr int D0 = 256;        // in dim
constexpr int D1 = 128;        // hidden 1
constexpr int D2 = 64;         // hidden 2

constexpr int BSHIFT = 9;                       // 512 nodes per bucket
constexpr int NPB = 1 << BSHIFT;                // 512
constexpr int NBUCK = (NN + NPB - 1) >> BSHIFT; // 196
constexpr int PBLK = 256;                       // partition blocks
constexpr int CHUNK = (NE + PBLK - 1) / PBLK;   // 12500

typedef unsigned short ushort8v __attribute__((ext_vector_type(8)));

static __device__ __forceinline__ float bf2f(unsigned short u) {
  return __uint_as_float(((unsigned)u) << 16);
}
static __device__ __forceinline__ unsigned short f2bf(float x) {
  unsigned u = __float_as_uint(x);
  unsigned r = (u + 0x7FFFu + ((u >> 16) & 1u)) >> 16;   // RNE
  return (unsigned short)r;
}

// ---------------- phase 1a: bucket counts (LDS histogram, few global atomics)
__global__ __launch_bounds__(256) void count_bucket_k(const int* __restrict__ rows,
                                                      unsigned* __restrict__ gcnt) {
  __shared__ unsigned hist[NBUCK];
  int tid = threadIdx.x;
  for (int i = tid; i < NBUCK; i += 256) hist[i] = 0;
  __syncthreads();
  int s = blockIdx.x * CHUNK;
  int e = s + CHUNK; if (e > NE) e = NE;
  for (int i = s + tid; i < e; i += 256)
    atomicAdd(&hist[((unsigned)rows[i]) >> BSHIFT], 1u);
  __syncthreads();
  for (int i = tid; i < NBUCK; i += 256)
    if (hist[i]) atomicAdd(&gcnt[i], hist[i]);
}

// ---------------- phase 1b: scan bucket counts -> boff, init cursors --------
__global__ __launch_bounds__(256) void bucket_scan_k(const unsigned* __restrict__ gcnt,
                                                     unsigned* __restrict__ boff,
                                                     unsigned* __restrict__ gcursor) {
  __shared__ unsigned s[256];
  int t = threadIdx.x;
  unsigned v = (t < NBUCK) ? gcnt[t] : 0u;
  s[t] = v;
  __syncthreads();
  for (int off = 1; off < 256; off <<= 1) {
    unsigned u = (t >= off) ? s[t - off] : 0u;
    __syncthreads();
    s[t] += u;
    __syncthreads();
  }
  if (t < NBUCK) {
    boff[t + 1] = s[t];          // inclusive -> boff[b+1]
    gcursor[t] = s[t] - v;       // exclusive (start cursor)
  }
  if (t == 0) boff[0] = 0u;
}

// ---------------- phase 1c: partition edges into buckets (dense writes) -----
__global__ __launch_bounds__(256) void partition_k(const int* __restrict__ rows,
                                                   const int* __restrict__ cols,
                                                   unsigned* __restrict__ gcursor,
                                                   unsigned* __restrict__ bucketed) {
  __shared__ unsigned hist[NBUCK], base[NBUCK];
  int tid = threadIdx.x;
  for (int i = tid; i < NBUCK; i += 256) hist[i] = 0;
  __syncthreads();
  int s = blockIdx.x * CHUNK;
  int e = s + CHUNK; if (e > NE) e = NE;
  for (int i = s + tid; i < e; i += 256)
    atomicAdd(&hist[((unsigned)rows[i]) >> BSHIFT], 1u);
  __syncthreads();
  for (int i = tid; i < NBUCK; i += 256)
    base[i] = hist[i] ? atomicAdd(&gcursor[i], hist[i]) : 0u;
  __syncthreads();
  for (int i = tid; i < NBUCK; i += 256) hist[i] = 0;
  __syncthreads();
  for (int i = s + tid; i < e; i += 256) {
    unsigned r = (unsigned)rows[i];
    unsigned b = r >> BSHIFT;
    unsigned p = ((r & (unsigned)(NPB - 1)) << 17) | (unsigned)cols[i];
    unsigned pos = base[b] + atomicAdd(&hist[b], 1u);
    bucketed[pos] = p;
  }
}

// ---------------- phase 2: per-bucket CSR build (all-local, dense) ----------
__global__ __launch_bounds__(256) void build_k(const unsigned* __restrict__ bucketed,
                                               const unsigned* __restrict__ boff,
                                               unsigned* __restrict__ row_start,
                                               float* __restrict__ dinv,
                                               int* __restrict__ col_sorted) {
  __shared__ unsigned hist[NPB], sc[NPB], cur[NPB];
  const int b = blockIdx.x, tid = threadIdx.x;
  hist[tid] = 0; hist[tid + 256] = 0;
  __syncthreads();
  const unsigned s0 = boff[b], e0 = boff[b + 1];
  for (unsigned i = s0 + tid; i < e0; i += 256)
    atomicAdd(&hist[bucketed[i] >> 17], 1u);
  __syncthreads();
  sc[tid] = hist[tid]; sc[tid + 256] = hist[tid + 256];
  __syncthreads();
  for (int off = 1; off < NPB; off <<= 1) {     // inclusive scan over 512
    unsigned v0 = (tid >= off) ? sc[tid - off] : 0u;
    unsigned v1 = (tid + 256 >= off) ? sc[tid + 256 - off] : 0u;
    __syncthreads();
    sc[tid] += v0; sc[tid + 256] += v1;
    __syncthreads();
  }
  cur[tid] = tid ? sc[tid - 1] : 0u;           // exclusive
  cur[tid + 256] = sc[tid + 255];
  for (int idx = tid; idx <= NPB; idx += 256) {
    int node = b * NPB + idx;
    if (node <= NN) {
      unsigned ex = idx ? sc[idx - 1] : 0u;
      row_start[node] = s0 + ex;
      if (idx < NPB && node < NN) dinv[node] = rsqrtf((float)hist[idx] + 1.0f);
    }
  }
  __syncthreads();
  for (unsigned i = s0 + tid; i < e0; i += 256) {
    unsigned p = bucketed[i];
    unsigned pos = s0 + atomicAdd(&cur[p >> 17], 1u);
    col_sorted[pos] = (int)(p & 0x1FFFFu);
  }
}

// ---------------- tiled fp32 GEMM, dinv epilogue scale, optional bf16 out ----
// out[r][c] = dinv[r] * sum_k A[r][k] * W[k][c]      (BN == full output width)
template <int BM, int BN, int BK, int TM, int TN, int K, bool BF16_OUT>
__global__ __launch_bounds__(256) void gemm_scale_k(const float* __restrict__ A,
                                                    const float* __restrict__ W,
                                                    const float* __restrict__ dinv,
                                                    void* __restrict__ outp, int M) {
  constexpr int TX = BN / TN;
  constexpr int TY = BM / TM;
  static_assert(TX * TY == 256, "thread shape");
  __shared__ float As[BK][BM];   // A tile, transposed
  __shared__ float Ws[BK][BN];   // W tile
  const int tid = threadIdx.x;
  const int tx = tid % TX, ty = tid / TX;
  const int rowBase = blockIdx.x * BM;

  float acc[TM][TN];
#pragma unroll
  for (int i = 0; i < TM; i++)
#pragma unroll
    for (int j = 0; j < TN; j++) acc[i][j] = 0.f;

  constexpr int AF4 = BM * BK / 4 / 256;
  constexpr int WF4 = BK * BN / 4 / 256;

  for (int k0 = 0; k0 < K; k0 += BK) {
#pragma unroll
    for (int q = 0; q < AF4; q++) {
      int f = tid + q * 256;
      int r = f / (BK / 4);
      int kk = (f % (BK / 4)) * 4;
      float4 v = make_float4(0.f, 0.f, 0.f, 0.f);
      int gr = rowBase + r;
      if (gr < M) v = *(const float4*)&A[(size_t)gr * K + k0 + kk];
      As[kk + 0][r] = v.x;
      As[kk + 1][r] = v.y;
      As[kk + 2][r] = v.z;
      As[kk + 3][r] = v.w;
    }
#pragma unroll
    for (int q = 0; q < WF4; q++) {
      int f = tid + q * 256;
      int kk = f / (BN / 4);
      int c = (f % (BN / 4)) * 4;
      *(float4*)&Ws[kk][c] = *(const float4*)&W[(size_t)(k0 + kk) * BN + c];
    }
    __syncthreads();
#pragma unroll
    for (int kk = 0; kk < BK; kk++) {
      float a[TM], wv[TN];
#pragma unroll
      for (int i = 0; i < TM; i += 4) {
        float4 t = *(const float4*)&As[kk][ty * TM + i];
        a[i] = t.x; a[i + 1] = t.y; a[i + 2] = t.z; a[i + 3] = t.w;
      }
#pragma unroll
      for (int j = 0; j < TN; j += 4) {
        float4 t = *(const float4*)&Ws[kk][tx * TN + j];
        wv[j] = t.x; wv[j + 1] = t.y; wv[j + 2] = t.z; wv[j + 3] = t.w;
      }
#pragma unroll
      for (int i = 0; i < TM; i++)
#pragma unroll
        for (int j = 0; j < TN; j++) acc[i][j] += a[i] * wv[j];
    }
    __syncthreads();
  }

#pragma unroll
  for (int i = 0; i < TM; i++) {
    int gr = rowBase + ty * TM + i;
    if (gr < M) {
      float d = dinv[gr];
      if constexpr (BF16_OUT) {
        unsigned short* out = (unsigned short*)outp;
#pragma unroll
        for (int j = 0; j < TN; j += 4) {
          ushort4 o;
          o.x = f2bf(acc[i][j + 0] * d);
          o.y = f2bf(acc[i][j + 1] * d);
          o.z = f2bf(acc[i][j + 2] * d);
          o.w = f2bf(acc[i][j + 3] * d);
          *(ushort4*)&out[(size_t)gr * BN + tx * TN + j] = o;
        }
      } else {
        float* out = (float*)outp;
#pragma unroll
        for (int j = 0; j < TN; j += 4) {
          float4 o;
          o.x = acc[i][j + 0] * d;
          o.y = acc[i][j + 1] * d;
          o.z = acc[i][j + 2] * d;
          o.w = acc[i][j + 3] * d;
          *(float4*)&out[(size_t)gr * BN + tx * TN + j] = o;
        }
      }
    }
  }
}

// ---------------- propagation: wave-per-node, bf16 payload gather ----------
// layer 1: 128 bf16 feats/row (256B). 16 lanes x 16B cover a row ->
// 4 neighbors per wave-load.
__global__ __launch_bounds__(256) void prop1_k(const unsigned short* __restrict__ hp,
                                               const unsigned* __restrict__ row_start,
                                               const int* __restrict__ cols,
                                               const float* __restrict__ dinv,
                                               const float* __restrict__ bias,
                                               float* __restrict__ out) {  // h1 f32 [NN][128]
  int wid = (blockIdx.x * 256 + threadIdx.x) >> 6;
  int lane = threadIdx.x & 63;
  if (wid >= NN) return;
  const int r = wid;
  const int q = lane >> 4, f = lane & 15;

  float a0[8], a1[8];
#pragma unroll
  for (int k = 0; k < 8; k++) { a0[k] = 0.f; a1[k] = 0.f; }
  if (q == 0) {  // self loop, counted once
    ushort8v v = *(const ushort8v*)(hp + (size_t)r * D1 + f * 8);
#pragma unroll
    for (int k = 0; k < 8; k++) a0[k] = bf2f(v[k]);
  }

  unsigned s = row_start[r], e = row_start[r + 1];
  for (unsigned base = s; base < e; base += 64) {
    int cnt = (int)min(64u, e - base);
    int c = (lane < cnt) ? cols[base + lane] : 0;
    int j = 0;
    for (; j + 8 <= cnt; j += 8) {
      int c0 = __shfl(c, j + q);
      int c1 = __shfl(c, j + 4 + q);
      ushort8v v0 = *(const ushort8v*)(hp + (size_t)c0 * D1 + f * 8);
      ushort8v v1 = *(const ushort8v*)(hp + (size_t)c1 * D1 + f * 8);
#pragma unroll
      for (int k = 0; k < 8; k++) a0[k] += bf2f(v0[k]);
#pragma unroll
      for (int k = 0; k < 8; k++) a1[k] += bf2f(v1[k]);
    }
    for (; j + 4 <= cnt; j += 4) {
      int c0 = __shfl(c, j + q);
      ushort8v v0 = *(const ushort8v*)(hp + (size_t)c0 * D1 + f * 8);
#pragma unroll
      for (int k = 0; k < 8; k++) a0[k] += bf2f(v0[k]);
    }
    if (j < cnt) {
      int c0 = __shfl(c, j + q);
      if (j + q < cnt) {
        ushort8v v0 = *(const ushort8v*)(hp + (size_t)c0 * D1 + f * 8);
#pragma unroll
        for (int k = 0; k < 8; k++) a0[k] += bf2f(v0[k]);
      }
    }
  }

#pragma unroll
  for (int k = 0; k < 8; k++) a0[k] += a1[k];
#pragma unroll
  for (int k = 0; k < 8; k++) a0[k] += __shfl_xor(a0[k], 16);
#pragma unroll
  for (int k = 0; k < 8; k++) a0[k] += __shfl_xor(a0[k], 32);

  if (q == 0) {
    float dr = dinv[r];
    float4 b0 = *(const float4*)&bias[f * 8];
    float4 b1v = *(const float4*)&bias[f * 8 + 4];
    float4 o0, o1;
    o0.x = fmaxf(a0[0] * dr + b0.x, 0.f);
    o0.y = fmaxf(a0[1] * dr + b0.y, 0.f);
    o0.z = fmaxf(a0[2] * dr + b0.z, 0.f);
    o0.w = fmaxf(a0[3] * dr + b0.w, 0.f);
    o1.x = fmaxf(a0[4] * dr + b1v.x, 0.f);
    o1.y = fmaxf(a0[5] * dr + b1v.y, 0.f);
    o1.z = fmaxf(a0[6] * dr + b1v.z, 0.f);
    o1.w = fmaxf(a0[7] * dr + b1v.w, 0.f);
    *(float4*)&out[(size_t)r * D1 + f * 8] = o0;
    *(float4*)&out[(size_t)r * D1 + f * 8 + 4] = o1;
  }
}

// layer 2: 64 bf16 feats/row (128B). 8 lanes x 16B -> 8 neighbors per load.
__global__ __launch_bounds__(256) void prop2_k(const unsigned short* __restrict__ hp,
                                               const unsigned* __restrict__ row_start,
                                               const int* __restrict__ cols,
                                               const float* __restrict__ dinv,
                                               const float* __restrict__ bias,
                                               float* __restrict__ out) {  // z f32 [NN][64]
  int wid = (blockIdx.x * 256 + threadIdx.x) >> 6;
  int lane = threadIdx.x & 63;
  if (wid >= NN) return;
  const int r = wid;
  const int q = lane >> 3, f = lane & 7;

  float a0[8], a1[8];
#pragma unroll
  for (int k = 0; k < 8; k++) { a0[k] = 0.f; a1[k] = 0.f; }
  if (q == 0) {  // self loop
    ushort8v v = *(const ushort8v*)(hp + (size_t)r * D2 + f * 8);
#pragma unroll
    for (int k = 0; k < 8; k++) a0[k] = bf2f(v[k]);
  }

  unsigned s = row_start[r], e = row_start[r + 1];
  for (unsigned base = s; base < e; base += 64) {
    int cnt = (int)min(64u, e - base);
    int c = (lane < cnt) ? cols[base + lane] : 0;
    int j = 0;
    for (; j + 16 <= cnt; j += 16) {
      int c0 = __shfl(c, j + q);
      int c1 = __shfl(c, j + 8 + q);
      ushort8v v0 = *(const ushort8v*)(hp + (size_t)c0 * D2 + f * 8);
      ushort8v v1 = *(const ushort8v*)(hp + (size_t)c1 * D2 + f * 8);
#pragma unroll
      for (int k = 0; k < 8; k++) a0[k] += bf2f(v0[k]);
#pragma unroll
      for (int k = 0; k < 8; k++) a1[k] += bf2f(v1[k]);
    }
    for (; j + 8 <= cnt; j += 8) {
      int c0 = __shfl(c, j + q);
      ushort8v v0 = *(const ushort8v*)(hp + (size_t)c0 * D2 + f * 8);
#pragma unroll
      for (int k = 0; k < 8; k++) a0[k] += bf2f(v0[k]);
    }
    if (j < cnt) {
      int c0 = __shfl(c, j + q);
      if (j + q < cnt) {
        ushort8v v0 = *(const ushort8v*)(hp + (size_t)c0 * D2 + f * 8);
#pragma unroll
        for (int k = 0; k < 8; k++) a0[k] += bf2f(v0[k]);
      }
    }
  }

#pragma unroll
  for (int k = 0; k < 8; k++) a0[k] += a1[k];
#pragma unroll
  for (int k = 0; k < 8; k++) a0[k] += __shfl_xor(a0[k], 8);
#pragma unroll
  for (int k = 0; k < 8; k++) a0[k] += __shfl_xor(a0[k], 16);
#pragma unroll
  for (int k = 0; k < 8; k++) a0[k] += __shfl_xor(a0[k], 32);

  if (q == 0) {
    float dr = dinv[r];
    float4 b0 = *(const float4*)&bias[f * 8];
    float4 b1v = *(const float4*)&bias[f * 8 + 4];
    float4 o0, o1;
    o0.x = fmaxf(a0[0] * dr + b0.x, 0.f);
    o0.y = fmaxf(a0[1] * dr + b0.y, 0.f);
    o0.z = fmaxf(a0[2] * dr + b0.z, 0.f);
    o0.w = fmaxf(a0[3] * dr + b0.w, 0.f);
    o1.x = fmaxf(a0[4] * dr + b1v.x, 0.f);
    o1.y = fmaxf(a0[5] * dr + b1v.y, 0.f);
    o1.z = fmaxf(a0[6] * dr + b1v.z, 0.f);
    o1.w = fmaxf(a0[7] * dr + b1v.w, 0.f);
    *(float4*)&out[(size_t)r * D2 + f * 8] = o0;
    *(float4*)&out[(size_t)r * D2 + f * 8 + 4] = o1;
  }
}

// ---------------- launcher ----------------
extern "C" void kernel_launch(void* const* d_in, const int* in_sizes, int n_in,
                              void* d_out, int out_size, void* d_ws, size_t ws_size,
                              hipStream_t stream) {
  const float* x = (const float*)d_in[0];
  const int* ei = (const int*)d_in[1];       // int64 in reference -> int32 here
  const float* W1 = (const float*)d_in[2];
  const float* b1 = (const float*)d_in[3];
  const float* W2 = (const float*)d_in[4];
  const float* b2 = (const float*)d_in[5];
  float* z = (float*)d_out;

  const int* rows = ei;         // edge_index[0] (targets)
  const int* cols = ei + NE;    // edge_index[1] (sources)

  auto align_up = [](size_t v) { return (v + 511) & ~(size_t)511; };
  char* w = (char*)d_ws;
  unsigned* gcnt = (unsigned*)w;       w += align_up((size_t)NBUCK * 4);
  unsigned* boff = (unsigned*)w;       w += align_up((size_t)(NBUCK + 1) * 4);
  unsigned* gcursor = (unsigned*)w;    w += align_up((size_t)NBUCK * 4);
  unsigned* row_start = (unsigned*)w;  w += align_up((size_t)(NN + 1) * 4);
  float* dinv = (float*)w;             w += align_up((size_t)NN * 4);
  int* col_sorted = (int*)w;           w += align_up((size_t)NE * 4);
  unsigned short* hbf = (unsigned short*)w; w += align_up((size_t)NN * D1 * 2);  // h'/h2' bf16
  float* h1 = (float*)w;               w += align_up((size_t)NN * D1 * 4);       // h1 f32
  unsigned* bucketed = (unsigned*)h1;  // aliases h1: dead before prop1 writes h1

  hipMemsetAsync(gcnt, 0, (size_t)NBUCK * 4, stream);

  count_bucket_k<<<PBLK, 256, 0, stream>>>(rows, gcnt);
  bucket_scan_k<<<1, 256, 0, stream>>>(gcnt, boff, gcursor);
  partition_k<<<PBLK, 256, 0, stream>>>(rows, cols, gcursor, bucketed);
  build_k<<<NBUCK, 256, 0, stream>>>(bucketed, boff, row_start, dinv, col_sorted);

  // layer 1: h' = bf16((x @ W1) * dinv) ; h1 = relu(dinv*(sum_nb h' + h'_self) + b1)
  gemm_scale_k<64, 128, 32, 8, 4, 256, true>
      <<<(NN + 63) / 64, 256, 0, stream>>>(x, W1, dinv, hbf, NN);
  prop1_k<<<(NN + 3) / 4, 256, 0, stream>>>(hbf, row_start, col_sorted, dinv, b1, h1);

  // layer 2: h2' = bf16((h1 @ W2) * dinv) ; z = relu(dinv*(sum + self) + b2)
  gemm_scale_k<64, 64, 32, 4, 4, 128, true>
      <<<(NN + 63) / 64, 256, 0, stream>>>(h1, W2, dinv, hbf, NN);
  prop2_k<<<(NN + 3) / 4, 256, 0, stream>>>(hbf, row_start, col_sorted, dinv, b2, z);
}

// Round 5
// 530.995 us; speedup vs baseline: 1.6651x; 1.0122x over previous
//
#include <hip/hip_runtime.h>

constexpr int NN = 100000;     // nodes
constexpr int NE = 3200000;    // edges
constexpr int D0 = 256;        // in dim
constexpr int D1 = 128;        // hidden 1
constexpr int D2 = 64;         // hidden 2

constexpr int BSHIFT = 9;                       // 512 nodes per bucket
constexpr int NPB = 1 << BSHIFT;                // 512
constexpr int NBUCK = (NN + NPB - 1) >> BSHIFT; // 196
constexpr int PBLK = 256;                       // partition blocks
constexpr int CHUNK = (NE + PBLK - 1) / PBLK;   // 12500

typedef unsigned short ushort8v __attribute__((ext_vector_type(8)));
typedef short short8v __attribute__((ext_vector_type(8)));
typedef float float4v __attribute__((ext_vector_type(4)));

static __device__ __forceinline__ float bf2f(unsigned short u) {
  return __uint_as_float(((unsigned)u) << 16);
}
static __device__ __forceinline__ unsigned short f2bf(float x) {
  unsigned u = __float_as_uint(x);
  unsigned r = (u + 0x7FFFu + ((u >> 16) & 1u)) >> 16;   // RNE
  return (unsigned short)r;
}

// ---------------- phase 1a: bucket counts (LDS histogram) -------------------
__global__ __launch_bounds__(256) void count_bucket_k(const int* __restrict__ rows,
                                                      unsigned* __restrict__ gcnt) {
  __shared__ unsigned hist[NBUCK];
  int tid = threadIdx.x;
  for (int i = tid; i < NBUCK; i += 256) hist[i] = 0;
  __syncthreads();
  int s = blockIdx.x * CHUNK;
  int e = s + CHUNK; if (e > NE) e = NE;
  for (int i = s + tid; i < e; i += 256)
    atomicAdd(&hist[((unsigned)rows[i]) >> BSHIFT], 1u);
  __syncthreads();
  for (int i = tid; i < NBUCK; i += 256)
    if (hist[i]) atomicAdd(&gcnt[i], hist[i]);
}

// ---------------- phase 1b: scan bucket counts -> boff, init cursors --------
__global__ __launch_bounds__(256) void bucket_scan_k(const unsigned* __restrict__ gcnt,
                                                     unsigned* __restrict__ boff,
                                                     unsigned* __restrict__ gcursor) {
  __shared__ unsigned s[256];
  int t = threadIdx.x;
  unsigned v = (t < NBUCK) ? gcnt[t] : 0u;
  s[t] = v;
  __syncthreads();
  for (int off = 1; off < 256; off <<= 1) {
    unsigned u = (t >= off) ? s[t - off] : 0u;
    __syncthreads();
    s[t] += u;
    __syncthreads();
  }
  if (t < NBUCK) {
    boff[t + 1] = s[t];
    gcursor[t] = s[t] - v;
  }
  if (t == 0) boff[0] = 0u;
}

// ---------------- phase 1c: partition edges into buckets --------------------
__global__ __launch_bounds__(256) void partition_k(const int* __restrict__ rows,
                                                   const int* __restrict__ cols,
                                                   unsigned* __restrict__ gcursor,
                                                   unsigned* __restrict__ bucketed) {
  __shared__ unsigned hist[NBUCK], base[NBUCK];
  int tid = threadIdx.x;
  for (int i = tid; i < NBUCK; i += 256) hist[i] = 0;
  __syncthreads();
  int s = blockIdx.x * CHUNK;
  int e = s + CHUNK; if (e > NE) e = NE;
  for (int i = s + tid; i < e; i += 256)
    atomicAdd(&hist[((unsigned)rows[i]) >> BSHIFT], 1u);
  __syncthreads();
  for (int i = tid; i < NBUCK; i += 256)
    base[i] = hist[i] ? atomicAdd(&gcursor[i], hist[i]) : 0u;
  __syncthreads();
  for (int i = tid; i < NBUCK; i += 256) hist[i] = 0;
  __syncthreads();
  for (int i = s + tid; i < e; i += 256) {
    unsigned r = (unsigned)rows[i];
    unsigned b = r >> BSHIFT;
    unsigned p = ((r & (unsigned)(NPB - 1)) << 17) | (unsigned)cols[i];
    unsigned pos = base[b] + atomicAdd(&hist[b], 1u);
    bucketed[pos] = p;
  }
}

// ---------------- phase 2: per-bucket CSR build -----------------------------
__global__ __launch_bounds__(256) void build_k(const unsigned* __restrict__ bucketed,
                                               const unsigned* __restrict__ boff,
                                               unsigned* __restrict__ row_start,
                                               float* __restrict__ dinv,
                                               int* __restrict__ col_sorted) {
  __shared__ unsigned hist[NPB], sc[NPB], cur[NPB];
  const int b = blockIdx.x, tid = threadIdx.x;
  hist[tid] = 0; hist[tid + 256] = 0;
  __syncthreads();
  const unsigned s0 = boff[b], e0 = boff[b + 1];
  for (unsigned i = s0 + tid; i < e0; i += 256)
    atomicAdd(&hist[bucketed[i] >> 17], 1u);
  __syncthreads();
  sc[tid] = hist[tid]; sc[tid + 256] = hist[tid + 256];
  __syncthreads();
  for (int off = 1; off < NPB; off <<= 1) {
    unsigned v0 = (tid >= off) ? sc[tid - off] : 0u;
    unsigned v1 = (tid + 256 >= off) ? sc[tid + 256 - off] : 0u;
    __syncthreads();
    sc[tid] += v0; sc[tid + 256] += v1;
    __syncthreads();
  }
  cur[tid] = tid ? sc[tid - 1] : 0u;
  cur[tid + 256] = sc[tid + 255];
  for (int idx = tid; idx <= NPB; idx += 256) {
    int node = b * NPB + idx;
    if (node <= NN) {
      unsigned ex = idx ? sc[idx - 1] : 0u;
      row_start[node] = s0 + ex;
      if (idx < NPB && node < NN) dinv[node] = rsqrtf((float)hist[idx] + 1.0f);
    }
  }
  __syncthreads();
  for (unsigned i = s0 + tid; i < e0; i += 256) {
    unsigned p = bucketed[i];
    unsigned pos = s0 + atomicAdd(&cur[p >> 17], 1u);
    col_sorted[pos] = (int)(p & 0x1FFFFu);
  }
}

// ---------------- MFMA bf16 GEMM with dinv epilogue, bf16 out ---------------
// out[r][c] = bf16( dinv[r] * sum_k A[r][k]*W[k][c] ), N == BN (full width).
// 4 waves in 2x2 grid; wave tile (BM/2)x(BN/2); 16x16x32 MFMA; BK=32.
template <int BM, int BN, int K>
__global__ __launch_bounds__(256) void mfma_gemm_k(const float* __restrict__ A,
                                                   const float* __restrict__ W,
                                                   const float* __restrict__ dinv,
                                                   unsigned short* __restrict__ out,
                                                   int M) {
  constexpr int MR = BM / 2 / 16;
  constexpr int NR = BN / 2 / 16;
  __shared__ __align__(16) unsigned short As[BM * 32];
  __shared__ __align__(16) unsigned short Ws[BN * 32];
  const int tid = threadIdx.x;
  const int lane = tid & 63;
  const int wid = tid >> 6;
  const int wr = (wid >> 1) * (BM / 2);
  const int wc = (wid & 1) * (BN / 2);
  const int rowBase = blockIdx.x * BM;

  float4v acc[MR][NR];
#pragma unroll
  for (int i = 0; i < MR; i++)
#pragma unroll
    for (int j = 0; j < NR; j++) acc[i][j] = (float4v)0.f;

  const int lr = lane & 15;          // fragment row/col
  const int lk = (lane >> 4) << 3;   // k-slice start (0,8,16,24)

  for (int k0 = 0; k0 < K; k0 += 32) {
    // stage A tile: [BM][32] bf16, row-major
#pragma unroll
    for (int g = tid; g < BM * 8; g += 256) {
      int row = g >> 3, kg = g & 7;
      int grow = rowBase + row;
      float4 v = make_float4(0.f, 0.f, 0.f, 0.f);
      if (grow < M) v = *(const float4*)&A[(size_t)grow * K + k0 + kg * 4];
      ushort4 u;
      u.x = f2bf(v.x); u.y = f2bf(v.y); u.z = f2bf(v.z); u.w = f2bf(v.w);
      *(ushort4*)&As[row * 32 + kg * 4] = u;
    }
    // stage W^T tile: Ws[col][k] = W[k][col]
#pragma unroll
    for (int g = tid; g < BN * 8; g += 256) {
      int col = g % BN, kg = g / BN;
      int k = k0 + kg * 4;
      ushort4 u;
      u.x = f2bf(W[(size_t)(k + 0) * BN + col]);
      u.y = f2bf(W[(size_t)(k + 1) * BN + col]);
      u.z = f2bf(W[(size_t)(k + 2) * BN + col]);
      u.w = f2bf(W[(size_t)(k + 3) * BN + col]);
      *(ushort4*)&Ws[col * 32 + kg * 4] = u;
    }
    __syncthreads();

    short8v a[MR], b[NR];
#pragma unroll
    for (int mi = 0; mi < MR; mi++)
      a[mi] = *(const short8v*)&As[(wr + mi * 16 + lr) * 32 + lk];
#pragma unroll
    for (int ni = 0; ni < NR; ni++)
      b[ni] = *(const short8v*)&Ws[(wc + ni * 16 + lr) * 32 + lk];
#pragma unroll
    for (int mi = 0; mi < MR; mi++)
#pragma unroll
      for (int ni = 0; ni < NR; ni++)
        acc[mi][ni] = __builtin_amdgcn_mfma_f32_16x16x32_bf16(a[mi], b[ni], acc[mi][ni], 0, 0, 0);
    __syncthreads();
  }

  // epilogue: D layout row=(lane>>4)*4+r, col=lane&15
#pragma unroll
  for (int mi = 0; mi < MR; mi++) {
#pragma unroll
    for (int r = 0; r < 4; r++) {
      int grow = rowBase + wr + mi * 16 + (lane >> 4) * 4 + r;
      if (grow < M) {
        float dv = dinv[grow];
#pragma unroll
        for (int ni = 0; ni < NR; ni++) {
          int gcol = wc + ni * 16 + lr;
          out[(size_t)grow * BN + gcol] = f2bf(acc[mi][ni][r] * dv);
        }
      }
    }
  }
}

// ---------------- propagation: wave-per-node, bf16 payload gather ----------
// layer 1: 128 bf16 feats/row (256B). 16 lanes x 16B -> 4 neighbors/load.
__global__ __launch_bounds__(256) void prop1_k(const unsigned short* __restrict__ hp,
                                               const unsigned* __restrict__ row_start,
                                               const int* __restrict__ cols,
                                               const float* __restrict__ dinv,
                                               const float* __restrict__ bias,
                                               float* __restrict__ out) {  // h1 f32 [NN][128]
  int wid = (blockIdx.x * 256 + threadIdx.x) >> 6;
  int lane = threadIdx.x & 63;
  if (wid >= NN) return;
  const int r = wid;
  const int q = lane >> 4, f = lane & 15;

  float a0[8], a1[8], a2[8], a3[8];
#pragma unroll
  for (int k = 0; k < 8; k++) { a0[k] = 0.f; a1[k] = 0.f; a2[k] = 0.f; a3[k] = 0.f; }
  if (q == 0) {  // self loop
    ushort8v v = *(const ushort8v*)(hp + (size_t)r * D1 + f * 8);
#pragma unroll
    for (int k = 0; k < 8; k++) a0[k] = bf2f(v[k]);
  }

  unsigned s = row_start[r], e = row_start[r + 1];
  for (unsigned base = s; base < e; base += 64) {
    int cnt = (int)min(64u, e - base);
    int c = (lane < cnt) ? cols[base + lane] : 0;
    int j = 0;
    for (; j + 16 <= cnt; j += 16) {
      int c0 = __shfl(c, j + q), c1 = __shfl(c, j + 4 + q);
      int c2 = __shfl(c, j + 8 + q), c3 = __shfl(c, j + 12 + q);
      ushort8v v0 = *(const ushort8v*)(hp + (size_t)c0 * D1 + f * 8);
      ushort8v v1 = *(const ushort8v*)(hp + (size_t)c1 * D1 + f * 8);
      ushort8v v2 = *(const ushort8v*)(hp + (size_t)c2 * D1 + f * 8);
      ushort8v v3 = *(const ushort8v*)(hp + (size_t)c3 * D1 + f * 8);
#pragma unroll
      for (int k = 0; k < 8; k++) a0[k] += bf2f(v0[k]);
#pragma unroll
      for (int k = 0; k < 8; k++) a1[k] += bf2f(v1[k]);
#pragma unroll
      for (int k = 0; k < 8; k++) a2[k] += bf2f(v2[k]);
#pragma unroll
      for (int k = 0; k < 8; k++) a3[k] += bf2f(v3[k]);
    }
    for (; j + 8 <= cnt; j += 8) {
      int c0 = __shfl(c, j + q), c1 = __shfl(c, j + 4 + q);
      ushort8v v0 = *(const ushort8v*)(hp + (size_t)c0 * D1 + f * 8);
      ushort8v v1 = *(const ushort8v*)(hp + (size_t)c1 * D1 + f * 8);
#pragma unroll
      for (int k = 0; k < 8; k++) a0[k] += bf2f(v0[k]);
#pragma unroll
      for (int k = 0; k < 8; k++) a1[k] += bf2f(v1[k]);
    }
    for (; j + 4 <= cnt; j += 4) {
      int c0 = __shfl(c, j + q);
      ushort8v v0 = *(const ushort8v*)(hp + (size_t)c0 * D1 + f * 8);
#pragma unroll
      for (int k = 0; k < 8; k++) a0[k] += bf2f(v0[k]);
    }
    if (j < cnt) {
      int c0 = __shfl(c, j + q);
      if (j + q < cnt) {
        ushort8v v0 = *(const ushort8v*)(hp + (size_t)c0 * D1 + f * 8);
#pragma unroll
        for (int k = 0; k < 8; k++) a0[k] += bf2f(v0[k]);
      }
    }
  }

#pragma unroll
  for (int k = 0; k < 8; k++) a0[k] += a1[k] + a2[k] + a3[k];
#pragma unroll
  for (int k = 0; k < 8; k++) a0[k] += __shfl_xor(a0[k], 16);
#pragma unroll
  for (int k = 0; k < 8; k++) a0[k] += __shfl_xor(a0[k], 32);

  if (q == 0) {
    float dr = dinv[r];
    float4 b0 = *(const float4*)&bias[f * 8];
    float4 b1v = *(const float4*)&bias[f * 8 + 4];
    float4 o0, o1;
    o0.x = fmaxf(a0[0] * dr + b0.x, 0.f);
    o0.y = fmaxf(a0[1] * dr + b0.y, 0.f);
    o0.z = fmaxf(a0[2] * dr + b0.z, 0.f);
    o0.w = fmaxf(a0[3] * dr + b0.w, 0.f);
    o1.x = fmaxf(a0[4] * dr + b1v.x, 0.f);
    o1.y = fmaxf(a0[5] * dr + b1v.y, 0.f);
    o1.z = fmaxf(a0[6] * dr + b1v.z, 0.f);
    o1.w = fmaxf(a0[7] * dr + b1v.w, 0.f);
    *(float4*)&out[(size_t)r * D1 + f * 8] = o0;
    *(float4*)&out[(size_t)r * D1 + f * 8 + 4] = o1;
  }
}

// layer 2: 64 bf16 feats/row (128B). 8 lanes x 16B -> 8 neighbors/load.
__global__ __launch_bounds__(256) void prop2_k(const unsigned short* __restrict__ hp,
                                               const unsigned* __restrict__ row_start,
                                               const int* __restrict__ cols,
                                               const float* __restrict__ dinv,
                                               const float* __restrict__ bias,
                                               float* __restrict__ out) {  // z f32 [NN][64]
  int wid = (blockIdx.x * 256 + threadIdx.x) >> 6;
  int lane = threadIdx.x & 63;
  if (wid >= NN) return;
  const int r = wid;
  const int q = lane >> 3, f = lane & 7;

  float a0[8], a1[8], a2[8], a3[8];
#pragma unroll
  for (int k = 0; k < 8; k++) { a0[k] = 0.f; a1[k] = 0.f; a2[k] = 0.f; a3[k] = 0.f; }
  if (q == 0) {  // self loop
    ushort8v v = *(const ushort8v*)(hp + (size_t)r * D2 + f * 8);
#pragma unroll
    for (int k = 0; k < 8; k++) a0[k] = bf2f(v[k]);
  }

  unsigned s = row_start[r], e = row_start[r + 1];
  for (unsigned base = s; base < e; base += 64) {
    int cnt = (int)min(64u, e - base);
    int c = (lane < cnt) ? cols[base + lane] : 0;
    int j = 0;
    for (; j + 32 <= cnt; j += 32) {
      int c0 = __shfl(c, j + q), c1 = __shfl(c, j + 8 + q);
      int c2 = __shfl(c, j + 16 + q), c3 = __shfl(c, j + 24 + q);
      ushort8v v0 = *(const ushort8v*)(hp + (size_t)c0 * D2 + f * 8);
      ushort8v v1 = *(const ushort8v*)(hp + (size_t)c1 * D2 + f * 8);
      ushort8v v2 = *(const ushort8v*)(hp + (size_t)c2 * D2 + f * 8);
      ushort8v v3 = *(const ushort8v*)(hp + (size_t)c3 * D2 + f * 8);
#pragma unroll
      for (int k = 0; k < 8; k++) a0[k] += bf2f(v0[k]);
#pragma unroll
      for (int k = 0; k < 8; k++) a1[k] += bf2f(v1[k]);
#pragma unroll
      for (int k = 0; k < 8; k++) a2[k] += bf2f(v2[k]);
#pragma unroll
      for (int k = 0; k < 8; k++) a3[k] += bf2f(v3[k]);
    }
    for (; j + 16 <= cnt; j += 16) {
      int c0 = __shfl(c, j + q), c1 = __shfl(c, j + 8 + q);
      ushort8v v0 = *(const ushort8v*)(hp + (size_t)c0 * D2 + f * 8);
      ushort8v v1 = *(const ushort8v*)(hp + (size_t)c1 * D2 + f * 8);
#pragma unroll
      for (int k = 0; k < 8; k++) a0[k] += bf2f(v0[k]);
#pragma unroll
      for (int k = 0; k < 8; k++) a1[k] += bf2f(v1[k]);
    }
    for (; j + 8 <= cnt; j += 8) {
      int c0 = __shfl(c, j + q);
      ushort8v v0 = *(const ushort8v*)(hp + (size_t)c0 * D2 + f * 8);
#pragma unroll
      for (int k = 0; k < 8; k++) a0[k] += bf2f(v0[k]);
    }
    if (j < cnt) {
      int c0 = __shfl(c, j + q);
      if (j + q < cnt) {
        ushort8v v0 = *(const ushort8v*)(hp + (size_t)c0 * D2 + f * 8);
#pragma unroll
        for (int k = 0; k < 8; k++) a0[k] += bf2f(v0[k]);
      }
    }
  }

#pragma unroll
  for (int k = 0; k < 8; k++) a0[k] += a1[k] + a2[k] + a3[k];
#pragma unroll
  for (int k = 0; k < 8; k++) a0[k] += __shfl_xor(a0[k], 8);
#pragma unroll
  for (int k = 0; k < 8; k++) a0[k] += __shfl_xor(a0[k], 16);
#pragma unroll
  for (int k = 0; k < 8; k++) a0[k] += __shfl_xor(a0[k], 32);

  if (q == 0) {
    float dr = dinv[r];
    float4 b0 = *(const float4*)&bias[f * 8];
    float4 b1v = *(const float4*)&bias[f * 8 + 4];
    float4 o0, o1;
    o0.x = fmaxf(a0[0] * dr + b0.x, 0.f);
    o0.y = fmaxf(a0[1] * dr + b0.y, 0.f);
    o0.z = fmaxf(a0[2] * dr + b0.z, 0.f);
    o0.w = fmaxf(a0[3] * dr + b0.w, 0.f);
    o1.x = fmaxf(a0[4] * dr + b1v.x, 0.f);
    o1.y = fmaxf(a0[5] * dr + b1v.y, 0.f);
    o1.z = fmaxf(a0[6] * dr + b1v.z, 0.f);
    o1.w = fmaxf(a0[7] * dr + b1v.w, 0.f);
    *(float4*)&out[(size_t)r * D2 + f * 8] = o0;
    *(float4*)&out[(size_t)r * D2 + f * 8 + 4] = o1;
  }
}

// ---------------- launcher ----------------
extern "C" void kernel_launch(void* const* d_in, const int* in_sizes, int n_in,
                              void* d_out, int out_size, void* d_ws, size_t ws_size,
                              hipStream_t stream) {
  const float* x = (const float*)d_in[0];
  const int* ei = (const int*)d_in[1];       // int64 in reference -> int32 here
  const float* W1 = (const float*)d_in[2];
  const float* b1 = (const float*)d_in[3];
  const float* W2 = (const float*)d_in[4];
  const float* b2 = (const float*)d_in[5];
  float* z = (float*)d_out;

  const int* rows = ei;         // edge_index[0] (targets)
  const int* cols = ei + NE;    // edge_index[1] (sources)

  auto align_up = [](size_t v) { return (v + 511) & ~(size_t)511; };
  char* w = (char*)d_ws;
  unsigned* gcnt = (unsigned*)w;       w += align_up((size_t)NBUCK * 4);
  unsigned* boff = (unsigned*)w;       w += align_up((size_t)(NBUCK + 1) * 4);
  unsigned* gcursor = (unsigned*)w;    w += align_up((size_t)NBUCK * 4);
  unsigned* row_start = (unsigned*)w;  w += align_up((size_t)(NN + 1) * 4);
  float* dinv = (float*)w;             w += align_up((size_t)NN * 4);
  int* col_sorted = (int*)w;           w += align_up((size_t)NE * 4);
  unsigned short* hbf = (unsigned short*)w; w += align_up((size_t)NN * D1 * 2);  // h'/h2' bf16
  float* h1 = (float*)w;               w += align_up((size_t)NN * D1 * 4);       // h1 f32
  unsigned* bucketed = (unsigned*)h1;  // aliases h1: dead before prop1 writes h1

  hipMemsetAsync(gcnt, 0, (size_t)NBUCK * 4, stream);

  count_bucket_k<<<PBLK, 256, 0, stream>>>(rows, gcnt);
  bucket_scan_k<<<1, 256, 0, stream>>>(gcnt, boff, gcursor);
  partition_k<<<PBLK, 256, 0, stream>>>(rows, cols, gcursor, bucketed);
  build_k<<<NBUCK, 256, 0, stream>>>(bucketed, boff, row_start, dinv, col_sorted);

  // layer 1: h' = bf16((x @ W1) * dinv) ; h1 = relu(dinv*(sum_nb h' + self) + b1)
  mfma_gemm_k<128, 128, 256>
      <<<(NN + 127) / 128, 256, 0, stream>>>(x, W1, dinv, hbf, NN);
  prop1_k<<<(NN + 3) / 4, 256, 0, stream>>>(hbf, row_start, col_sorted, dinv, b1, h1);

  // layer 2: h2' = bf16((h1 @ W2) * dinv) ; z = relu(dinv*(sum + self) + b2)
  mfma_gemm_k<128, 64, 128>
      <<<(NN + 127) / 128, 256, 0, stream>>>(h1, W2, dinv, hbf, NN);
  prop2_k<<<(NN + 3) / 4, 256, 0, stream>>>(hbf, row_start, col_sorted, dinv, b2, z);
}

// Round 7
// 477.342 us; speedup vs baseline: 1.8523x; 1.1124x over previous
//
#include <hip/hip_runtime.h>

constexpr int NN = 100000;     // nodes
constexpr int NE = 3200000;    // edges
constexpr int D1 = 128;        // hidden 1
constexpr int D2 = 64;         // hidden 2

constexpr int BSHIFT = 9;                       // 512 nodes per bucket
constexpr int NPB = 1 << BSHIFT;                // 512
constexpr int NBUCK = (NN + NPB - 1) >> BSHIFT; // 196
constexpr int CAP = 18432;                      // bucket capacity: mean 16384 + 16 sigma
constexpr int PBLK = 256;                       // partition blocks
constexpr int CHUNK = (NE + PBLK - 1) / PBLK;   // 12500

typedef unsigned short ushort8v __attribute__((ext_vector_type(8)));
typedef short short8v __attribute__((ext_vector_type(8)));
typedef float float4v __attribute__((ext_vector_type(4)));

static __device__ __forceinline__ float bf2f(unsigned short u) {
  return __uint_as_float(((unsigned)u) << 16);
}
static __device__ __forceinline__ unsigned short f2bf(float x) {
  unsigned u = __float_as_uint(x);
  unsigned r = (u + 0x7FFFu + ((u >> 16) & 1u)) >> 16;   // RNE
  return (unsigned short)r;
}

// ---------------- partition edges into fixed-capacity buckets ---------------
__global__ __launch_bounds__(256) void partition_k(const int* __restrict__ rows,
                                                   const int* __restrict__ cols,
                                                   unsigned* __restrict__ gcursor,
                                                   unsigned* __restrict__ bucketed) {
  __shared__ unsigned hist[NBUCK], base[NBUCK];
  int tid = threadIdx.x;
  for (int i = tid; i < NBUCK; i += 256) hist[i] = 0;
  __syncthreads();
  int s = blockIdx.x * CHUNK;
  int e = s + CHUNK; if (e > NE) e = NE;
  for (int i = s + tid; i < e; i += 256)
    atomicAdd(&hist[((unsigned)rows[i]) >> BSHIFT], 1u);
  __syncthreads();
  for (int i = tid; i < NBUCK; i += 256)
    base[i] = hist[i] ? ((unsigned)i * CAP + atomicAdd(&gcursor[i], hist[i])) : 0u;
  __syncthreads();
  for (int i = tid; i < NBUCK; i += 256) hist[i] = 0;
  __syncthreads();
  for (int i = s + tid; i < e; i += 256) {
    unsigned r = (unsigned)rows[i];
    unsigned b = r >> BSHIFT;
    unsigned p = ((r & (unsigned)(NPB - 1)) << 17) | (unsigned)cols[i];
    unsigned pos = base[b] + atomicAdd(&hist[b], 1u);
    if (pos < (b + 1u) * (unsigned)CAP) bucketed[pos] = p;   // overflow guard (never expected)
  }
}

// ---------------- per-bucket CSR build (LDS-staged, 512 threads) ------------
__global__ __launch_bounds__(512) void build_k(const unsigned* __restrict__ bucketed,
                                               const unsigned* __restrict__ gcnt,
                                               unsigned* __restrict__ row_start,
                                               unsigned* __restrict__ degA,
                                               float* __restrict__ dinv,
                                               int* __restrict__ col_sorted) {
  __shared__ unsigned hist[NPB], sc[NPB], cur[NPB];
  __shared__ unsigned stage[CAP];
  const int b = blockIdx.x, tid = threadIdx.x;
  const unsigned gbase = (unsigned)b * CAP;
  unsigned cnt = gcnt[b]; if (cnt > (unsigned)CAP) cnt = CAP;
  hist[tid] = 0;
  __syncthreads();
  for (unsigned i = tid; i < cnt; i += 512) {
    unsigned p = bucketed[gbase + i];
    stage[i] = p;
    atomicAdd(&hist[p >> 17], 1u);
  }
  __syncthreads();
  sc[tid] = hist[tid];
  __syncthreads();
  for (int off = 1; off < NPB; off <<= 1) {   // inclusive scan over 512
    unsigned v = (tid >= off) ? sc[tid - off] : 0u;
    __syncthreads();
    sc[tid] += v;
    __syncthreads();
  }
  unsigned ex = sc[tid] - hist[tid];
  cur[tid] = ex;
  int node = b * NPB + tid;
  if (node < NN) {
    row_start[node] = gbase + ex;
    degA[node] = hist[tid];
    dinv[node] = rsqrtf((float)hist[tid] + 1.0f);
  }
  __syncthreads();
  for (unsigned i = tid; i < cnt; i += 512) {
    unsigned p = stage[i];
    unsigned pos = gbase + atomicAdd(&cur[p >> 17], 1u);
    col_sorted[pos] = (int)(p & 0x1FFFFu);
  }
}

// ---------------- MFMA bf16 GEMM, k-plane LDS layout (conflict-free) --------
// out[r][c] = bf16( dinv[r] * sum_k A[r][k]*W[k][c] ), N == BN (full width).
// LDS: [plane p=k/8][row][8 bf16], plane stride (B*+1) rows for bank spread.
template <int BM, int BN, int K, bool A_BF16>
__global__ __launch_bounds__(256) void mfma_gemm_k(const void* __restrict__ Ap,
                                                   const float* __restrict__ W,
                                                   const float* __restrict__ dinv,
                                                   unsigned short* __restrict__ out,
                                                   int M) {
  constexpr int MR = BM / 2 / 16;
  constexpr int NR = BN / 2 / 16;
  __shared__ __align__(16) unsigned short As[4 * (BM + 1) * 8];
  __shared__ __align__(16) unsigned short Ws[4 * (BN + 1) * 8];
  const int tid = threadIdx.x;
  const int lane = tid & 63;
  const int wid = tid >> 6;
  const int wr = (wid >> 1) * (BM / 2);
  const int wc = (wid & 1) * (BN / 2);
  const int rowBase = blockIdx.x * BM;

  float4v acc[MR][NR];
#pragma unroll
  for (int i = 0; i < MR; i++)
#pragma unroll
    for (int j = 0; j < NR; j++) acc[i][j] = (float4v)0.f;

  const int lr = lane & 15;       // fragment row/col within 16x16
  const int lp = lane >> 4;       // k-plane 0..3 (k = lp*8 .. lp*8+7)

  for (int k0 = 0; k0 < K; k0 += 32) {
    // ---- stage A: item g -> (row = g>>2, plane p = g&3), one b128 write
#pragma unroll
    for (int it = 0; it < BM * 4 / 256; it++) {
      int g = tid + it * 256;
      int row = g >> 2, p = g & 3;
      int grow = rowBase + row;
      ushort8v u;
      if (grow < M) {
        if constexpr (A_BF16) {
          u = *(const ushort8v*)((const unsigned short*)Ap + (size_t)grow * K + k0 + p * 8);
        } else {
          const float* A = (const float*)Ap;
          float4 v0 = *(const float4*)&A[(size_t)grow * K + k0 + p * 8];
          float4 v1 = *(const float4*)&A[(size_t)grow * K + k0 + p * 8 + 4];
          u[0] = f2bf(v0.x); u[1] = f2bf(v0.y); u[2] = f2bf(v0.z); u[3] = f2bf(v0.w);
          u[4] = f2bf(v1.x); u[5] = f2bf(v1.y); u[6] = f2bf(v1.z); u[7] = f2bf(v1.w);
        }
      } else {
#pragma unroll
        for (int j = 0; j < 8; j++) u[j] = 0;
      }
      *(ushort8v*)&As[(p * (BM + 1) + row) * 8] = u;
    }
    // ---- stage W^T: item g -> (col = g&(BN-1), plane p), one b128 write
#pragma unroll
    for (int it = 0; it < BN * 4 / 256; it++) {
      int g = tid + it * 256;
      int col = g & (BN - 1), p = g / BN;
      const float* wp = &W[(size_t)(k0 + p * 8) * BN + col];
      ushort8v u;
#pragma unroll
      for (int j = 0; j < 8; j++) u[j] = f2bf(wp[(size_t)j * BN]);
      *(ushort8v*)&Ws[(p * (BN + 1) + col) * 8] = u;
    }
    __syncthreads();

    short8v a[MR], bf[NR];
#pragma unroll
    for (int mi = 0; mi < MR; mi++)
      a[mi] = *(const short8v*)&As[(lp * (BM + 1) + wr + mi * 16 + lr) * 8];
#pragma unroll
    for (int ni = 0; ni < NR; ni++)
      bf[ni] = *(const short8v*)&Ws[(lp * (BN + 1) + wc + ni * 16 + lr) * 8];
#pragma unroll
    for (int mi = 0; mi < MR; mi++)
#pragma unroll
      for (int ni = 0; ni < NR; ni++)
        acc[mi][ni] = __builtin_amdgcn_mfma_f32_16x16x32_bf16(a[mi], bf[ni], acc[mi][ni], 0, 0, 0);
    __syncthreads();
  }

  // epilogue: D layout row=(lane>>4)*4+r, col=lane&15  (m89-verified)
#pragma unroll
  for (int mi = 0; mi < MR; mi++) {
#pragma unroll
    for (int r4 = 0; r4 < 4; r4++) {
      int grow = rowBase + wr + mi * 16 + (lane >> 4) * 4 + r4;
      if (grow < M) {
        float dv = dinv[grow];
#pragma unroll
        for (int ni = 0; ni < NR; ni++) {
          int gcol = wc + ni * 16 + lr;
          out[(size_t)grow * BN + gcol] = f2bf(acc[mi][ni][r4] * dv);
        }
      }
    }
  }
}

// ---------------- propagation: wave-per-node, bf16 payload gather ----------
// layer 1: 128 bf16 feats/row (256B). 16 lanes x 16B -> 4 neighbors/load.
__global__ __launch_bounds__(256) void prop1_k(const unsigned short* __restrict__ hp,
                                               const unsigned* __restrict__ row_start,
                                               const unsigned* __restrict__ degA,
                                               const int* __restrict__ cols,
                                               const float* __restrict__ dinv,
                                               const float* __restrict__ bias,
                                               unsigned short* __restrict__ out) {  // h1 bf16
  int wid = (blockIdx.x * 256 + threadIdx.x) >> 6;
  int lane = threadIdx.x & 63;
  if (wid >= NN) return;
  const int r = wid;
  const int q = lane >> 4, f = lane & 15;

  float a0[8], a1[8], a2[8], a3[8];
#pragma unroll
  for (int k = 0; k < 8; k++) { a0[k] = 0.f; a1[k] = 0.f; a2[k] = 0.f; a3[k] = 0.f; }
  if (q == 0) {  // self loop
    ushort8v v = *(const ushort8v*)(hp + (size_t)r * D1 + f * 8);
#pragma unroll
    for (int k = 0; k < 8; k++) a0[k] = bf2f(v[k]);
  }

  unsigned s = row_start[r], e = s + degA[r];
  for (unsigned base = s; base < e; base += 64) {
    int cnt = (int)min(64u, e - base);
    int c = (lane < cnt) ? cols[base + lane] : 0;
    int j = 0;
    for (; j + 16 <= cnt; j += 16) {
      int c0 = __shfl(c, j + q), c1 = __shfl(c, j + 4 + q);
      int c2 = __shfl(c, j + 8 + q), c3 = __shfl(c, j + 12 + q);
      ushort8v v0 = *(const ushort8v*)(hp + (size_t)c0 * D1 + f * 8);
      ushort8v v1 = *(const ushort8v*)(hp + (size_t)c1 * D1 + f * 8);
      ushort8v v2 = *(const ushort8v*)(hp + (size_t)c2 * D1 + f * 8);
      ushort8v v3 = *(const ushort8v*)(hp + (size_t)c3 * D1 + f * 8);
#pragma unroll
      for (int k = 0; k < 8; k++) a0[k] += bf2f(v0[k]);
#pragma unroll
      for (int k = 0; k < 8; k++) a1[k] += bf2f(v1[k]);
#pragma unroll
      for (int k = 0; k < 8; k++) a2[k] += bf2f(v2[k]);
#pragma unroll
      for (int k = 0; k < 8; k++) a3[k] += bf2f(v3[k]);
    }
    for (; j + 8 <= cnt; j += 8) {
      int c0 = __shfl(c, j + q), c1 = __shfl(c, j + 4 + q);
      ushort8v v0 = *(const ushort8v*)(hp + (size_t)c0 * D1 + f * 8);
      ushort8v v1 = *(const ushort8v*)(hp + (size_t)c1 * D1 + f * 8);
#pragma unroll
      for (int k = 0; k < 8; k++) a0[k] += bf2f(v0[k]);
#pragma unroll
      for (int k = 0; k < 8; k++) a1[k] += bf2f(v1[k]);
    }
    for (; j + 4 <= cnt; j += 4) {
      int c0 = __shfl(c, j + q);
      ushort8v v0 = *(const ushort8v*)(hp + (size_t)c0 * D1 + f * 8);
#pragma unroll
      for (int k = 0; k < 8; k++) a0[k] += bf2f(v0[k]);
    }
    if (j < cnt) {
      int c0 = __shfl(c, j + q);
      if (j + q < cnt) {
        ushort8v v0 = *(const ushort8v*)(hp + (size_t)c0 * D1 + f * 8);
#pragma unroll
        for (int k = 0; k < 8; k++) a0[k] += bf2f(v0[k]);
      }
    }
  }

#pragma unroll
  for (int k = 0; k < 8; k++) a0[k] += a1[k] + a2[k] + a3[k];
#pragma unroll
  for (int k = 0; k < 8; k++) a0[k] += __shfl_xor(a0[k], 16);
#pragma unroll
  for (int k = 0; k < 8; k++) a0[k] += __shfl_xor(a0[k], 32);

  if (q == 0) {
    float dr = dinv[r];
    float4 b0 = *(const float4*)&bias[f * 8];
    float4 b1v = *(const float4*)&bias[f * 8 + 4];
    ushort8v o;
    o[0] = f2bf(fmaxf(a0[0] * dr + b0.x, 0.f));
    o[1] = f2bf(fmaxf(a0[1] * dr + b0.y, 0.f));
    o[2] = f2bf(fmaxf(a0[2] * dr + b0.z, 0.f));
    o[3] = f2bf(fmaxf(a0[3] * dr + b0.w, 0.f));
    o[4] = f2bf(fmaxf(a0[4] * dr + b1v.x, 0.f));
    o[5] = f2bf(fmaxf(a0[5] * dr + b1v.y, 0.f));
    o[6] = f2bf(fmaxf(a0[6] * dr + b1v.z, 0.f));
    o[7] = f2bf(fmaxf(a0[7] * dr + b1v.w, 0.f));
    *(ushort8v*)&out[(size_t)r * D1 + f * 8] = o;
  }
}

// layer 2: 64 bf16 feats/row (128B). 8 lanes x 16B -> 8 neighbors/load.
__global__ __launch_bounds__(256) void prop2_k(const unsigned short* __restrict__ hp,
                                               const unsigned* __restrict__ row_start,
                                               const unsigned* __restrict__ degA,
                                               const int* __restrict__ cols,
                                               const float* __restrict__ dinv,
                                               const float* __restrict__ bias,
                                               float* __restrict__ out) {  // z f32 [NN][64]
  int wid = (blockIdx.x * 256 + threadIdx.x) >> 6;
  int lane = threadIdx.x & 63;
  if (wid >= NN) return;
  const int r = wid;
  const int q = lane >> 3, f = lane & 7;

  float a0[8], a1[8], a2[8], a3[8];
#pragma unroll
  for (int k = 0; k < 8; k++) { a0[k] = 0.f; a1[k] = 0.f; a2[k] = 0.f; a3[k] = 0.f; }
  if (q == 0) {  // self loop
    ushort8v v = *(const ushort8v*)(hp + (size_t)r * D2 + f * 8);
#pragma unroll
    for (int k = 0; k < 8; k++) a0[k] = bf2f(v[k]);
  }

  unsigned s = row_start[r], e = s + degA[r];
  for (unsigned base = s; base < e; base += 64) {
    int cnt = (int)min(64u, e - base);
    int c = (lane < cnt) ? cols[base + lane] : 0;
    int j = 0;
    for (; j + 32 <= cnt; j += 32) {
      int c0 = __shfl(c, j + q), c1 = __shfl(c, j + 8 + q);
      int c2 = __shfl(c, j + 16 + q), c3 = __shfl(c, j + 24 + q);
      ushort8v v0 = *(const ushort8v*)(hp + (size_t)c0 * D2 + f * 8);
      ushort8v v1 = *(const ushort8v*)(hp + (size_t)c1 * D2 + f * 8);
      ushort8v v2 = *(const ushort8v*)(hp + (size_t)c2 * D2 + f * 8);
      ushort8v v3 = *(const ushort8v*)(hp + (size_t)c3 * D2 + f * 8);
#pragma unroll
      for (int k = 0; k < 8; k++) a0[k] += bf2f(v0[k]);
#pragma unroll
      for (int k = 0; k < 8; k++) a1[k] += bf2f(v1[k]);
#pragma unroll
      for (int k = 0; k < 8; k++) a2[k] += bf2f(v2[k]);
#pragma unroll
      for (int k = 0; k < 8; k++) a3[k] += bf2f(v3[k]);
    }
    for (; j + 16 <= cnt; j += 16) {
      int c0 = __shfl(c, j + q), c1 = __shfl(c, j + 8 + q);
      ushort8v v0 = *(const ushort8v*)(hp + (size_t)c0 * D2 + f * 8);
      ushort8v v1 = *(const ushort8v*)(hp + (size_t)c1 * D2 + f * 8);
#pragma unroll
      for (int k = 0; k < 8; k++) a0[k] += bf2f(v0[k]);
#pragma unroll
      for (int k = 0; k < 8; k++) a1[k] += bf2f(v1[k]);
    }
    for (; j + 8 <= cnt; j += 8) {
      int c0 = __shfl(c, j + q);
      ushort8v v0 = *(const ushort8v*)(hp + (size_t)c0 * D2 + f * 8);
#pragma unroll
      for (int k = 0; k < 8; k++) a0[k] += bf2f(v0[k]);
    }
    if (j < cnt) {
      int c0 = __shfl(c, j + q);
      if (j + q < cnt) {
        ushort8v v0 = *(const ushort8v*)(hp + (size_t)c0 * D2 + f * 8);
#pragma unroll
        for (int k = 0; k < 8; k++) a0[k] += bf2f(v0[k]);
      }
    }
  }

#pragma unroll
  for (int k = 0; k < 8; k++) a0[k] += a1[k] + a2[k] + a3[k];
#pragma unroll
  for (int k = 0; k < 8; k++) a0[k] += __shfl_xor(a0[k], 8);
#pragma unroll
  for (int k = 0; k < 8; k++) a0[k] += __shfl_xor(a0[k], 16);
#pragma unroll
  for (int k = 0; k < 8; k++) a0[k] += __shfl_xor(a0[k], 32);

  if (q == 0) {
    float dr = dinv[r];
    float4 b0 = *(const float4*)&bias[f * 8];
    float4 b1v = *(const float4*)&bias[f * 8 + 4];
    float4 o0, o1;
    o0.x = fmaxf(a0[0] * dr + b0.x, 0.f);
    o0.y = fmaxf(a0[1] * dr + b0.y, 0.f);
    o0.z = fmaxf(a0[2] * dr + b0.z, 0.f);
    o0.w = fmaxf(a0[3] * dr + b0.w, 0.f);
    o1.x = fmaxf(a0[4] * dr + b1v.x, 0.f);
    o1.y = fmaxf(a0[5] * dr + b1v.y, 0.f);
    o1.z = fmaxf(a0[6] * dr + b1v.z, 0.f);
    o1.w = fmaxf(a0[7] * dr + b1v.w, 0.f);
    *(float4*)&out[(size_t)r * D2 + f * 8] = o0;
    *(float4*)&out[(size_t)r * D2 + f * 8 + 4] = o1;
  }
}

// ---------------- launcher ----------------
extern "C" void kernel_launch(void* const* d_in, const int* in_sizes, int n_in,
                              void* d_out, int out_size, void* d_ws, size_t ws_size,
                              hipStream_t stream) {
  const float* x = (const float*)d_in[0];
  const int* ei = (const int*)d_in[1];       // int64 in reference -> int32 here
  const float* W1 = (const float*)d_in[2];
  const float* b1 = (const float*)d_in[3];
  const float* W2 = (const float*)d_in[4];
  const float* b2 = (const float*)d_in[5];
  float* z = (float*)d_out;

  const int* rows = ei;         // edge_index[0] (targets)
  const int* cols = ei + NE;    // edge_index[1] (sources)

  auto align_up = [](size_t v) { return (v + 511) & ~(size_t)511; };
  char* w = (char*)d_ws;
  unsigned* gcursor = (unsigned*)w;    w += align_up((size_t)NBUCK * 4);
  unsigned* row_start = (unsigned*)w;  w += align_up((size_t)NN * 4);
  unsigned* degA = (unsigned*)w;       w += align_up((size_t)NN * 4);
  float* dinv = (float*)w;             w += align_up((size_t)NN * 4);
  int* col_sorted = (int*)w;           w += align_up((size_t)NBUCK * CAP * 4);
  unsigned short* hbf = (unsigned short*)w; w += align_up((size_t)NN * D1 * 2);  // h'/h2' bf16
  unsigned short* h1b = (unsigned short*)w; w += align_up((size_t)NN * D1 * 2);  // h1 bf16
  unsigned* bucketed = (unsigned*)h1b;  // aliases h1b: dead before prop1 writes h1

  hipMemsetAsync(gcursor, 0, (size_t)NBUCK * 4, stream);

  partition_k<<<PBLK, 256, 0, stream>>>(rows, cols, gcursor, bucketed);
  build_k<<<NBUCK, 512, 0, stream>>>(bucketed, gcursor, row_start, degA, dinv, col_sorted);

  // layer 1: h' = bf16((x @ W1) * dinv) ; h1 = relu(dinv*(sum_nb h' + self) + b1)
  mfma_gemm_k<128, 128, 256, false>
      <<<(NN + 127) / 128, 256, 0, stream>>>(x, W1, dinv, hbf, NN);
  prop1_k<<<(NN + 3) / 4, 256, 0, stream>>>(hbf, row_start, degA, col_sorted, dinv, b1, h1b);

  // layer 2: h2' = bf16((h1 @ W2) * dinv) ; z = relu(dinv*(sum + self) + b2)
  mfma_gemm_k<128, 64, 128, true>
      <<<(NN + 127) / 128, 256, 0, stream>>>(h1b, W2, dinv, hbf, NN);
  prop2_k<<<(NN + 3) / 4, 256, 0, stream>>>(hbf, row_start, degA, col_sorted, dinv, b2, z);
}